// Round 7
// baseline (315.914 us; speedup 1.0000x reference)
//
#include <hip/hip_runtime.h>

#define Hh 160
#define Ww 160
#define HW 25600
#define Bb 8
#define Cc 64
#define Oo 64
#define NPIX (Bb * HW)   // 204800

typedef __bf16 bf16x8 __attribute__((ext_vector_type(8)));
typedef float  f32x4  __attribute__((ext_vector_type(4)));
typedef float  f32x2  __attribute__((ext_vector_type(2)));

__device__ inline unsigned rnd_bf(float a) {
    unsigned u = __float_as_uint(a);
    return (u + 0x7FFFu + ((u >> 16) & 1u)) >> 16;   // RNE (prep only)
}
// fast round-half-up pack of two f32 -> packed bf16x2
__device__ inline unsigned pack_bf2(float a, float b) {
    unsigned ua = __float_as_uint(a) + 0x8000u;
    unsigned ub = __float_as_uint(b) + 0x8000u;
    return __builtin_amdgcn_perm(ub, ua, 0x07060302);
}
__device__ inline f32x2 up2(unsigned u) {
    f32x2 r;
    r.x = __uint_as_float(u << 16);
    r.y = __uint_as_float(u & 0xffff0000u);
    return r;
}
__device__ inline unsigned blend4(unsigned u00, unsigned u01, unsigned u10, unsigned u11,
                                  float w00, float w01, float w10, float w11) {
    f32x2 r = up2(u00) * w00 + up2(u01) * w01 + up2(u10) * w10 + up2(u11) * w11;
    return pack_bf2(r.x, r.y);
}
union UV { uint4 u; bf16x8 v; };
__device__ inline bf16x8 as_bf(uint4 u) { UV c; c.u = u; return c.v; }

// ---- init: [0..3199] NCHW->NHWC bf16 transpose; [3200..] weight swizzle ------
// wtbL : [k][half:2][nt:4][m:16][quad:4] 8-elem chunks; elem j -> w_dcn[o=nt*16+m][c=half*32+quad*8+j][k]
// woffL: [k][half:2][nt2:2][m:16][quad:4] chunks;       elem j -> w_off[o=nt2*16+m][c=half*32+quad*8+j][k]
__global__ __launch_bounds__(256) void init_kernel(
    const float* __restrict__ x, unsigned short* __restrict__ xhwc,
    const float* __restrict__ w_dcn, const float* __restrict__ b_dcn,
    const float* __restrict__ w_off,
    const float* __restrict__ gamma, const float* __restrict__ beta,
    const float* __restrict__ run_mean, const float* __restrict__ run_var,
    unsigned short* __restrict__ wtbL, unsigned short* __restrict__ woffL,
    float* __restrict__ scaleb)
{
    __shared__ float tile[64 * 65];
    int t = threadIdx.x;
    if (blockIdx.x < 3200) {
        int blk = blockIdx.x;
        int b = blk / 400, hw0 = (blk % 400) * 64;
        int lane = t & 63, grp = t >> 6;
        const float* xp = x + (size_t)b * Cc * HW + hw0 + lane;
#pragma unroll
        for (int i = 0; i < 16; ++i) {
            int c = i * 4 + grp;
            tile[lane * 65 + c] = xp[(size_t)c * HW];
        }
        __syncthreads();
        int px  = t >> 2;
        int ch0 = (t & 3) * 16;
        const float* row = tile + px * 65 + ch0;
        unsigned u[8];
#pragma unroll
        for (int j = 0; j < 8; ++j) u[j] = pack_bf2(row[2 * j], row[2 * j + 1]);
        unsigned short* dst = xhwc + ((size_t)(b * HW + hw0 + px)) * 64 + ch0;
        *(uint4*)dst       = make_uint4(u[0], u[1], u[2], u[3]);
        *(uint4*)(dst + 8) = make_uint4(u[4], u[5], u[6], u[7]);
    } else {
        int i = (blockIdx.x - 3200) * 256 + t;
        if (i < 9 * 4096) {                  // wtbL
            int k = i >> 12, r = i & 4095;
            int j = r & 7, quad = (r >> 3) & 3, mm = (r >> 5) & 15;
            int nt = (r >> 9) & 3, half = (r >> 11) & 1;
            int o = nt * 16 + mm, c = half * 32 + quad * 8 + j;
            wtbL[i] = (unsigned short)rnd_bf(w_dcn[(o * Cc + c) * 9 + k]);
        }
        if (i < 9 * 2048) {                  // woffL
            int k = i >> 11, r = i & 2047;
            int j = r & 7, quad = (r >> 3) & 3, mm = (r >> 5) & 15;
            int nt2 = (r >> 9) & 1, half = (r >> 10) & 1;
            int o = nt2 * 16 + mm, c = half * 32 + quad * 8 + j;
            woffL[i] = (o < 18) ? (unsigned short)rnd_bf(w_off[(o * Cc + c) * 9 + k])
                                : (unsigned short)0;
        }
        if (i < Oo) {
            float inv = gamma[i] * rsqrtf(run_var[i] + 1e-5f);
            scaleb[i]      = inv;
            scaleb[Oo + i] = b_dcn[i] * inv + (beta[i] - run_mean[i] * inv);
        }
    }
}

// issue the 8 corner loads + compute the 4 bilinear weights for one tap
__device__ inline void gather_tap(const unsigned short* __restrict__ xq,
                                  float py, float px, uint4 G[8], float W[4])
{
    float y0f = floorf(py), x0f = floorf(px);
    float fy = py - y0f, fx = px - x0f;
    int y0 = (int)y0f, x0i = (int)x0f;
    int y1 = y0 + 1, x1 = x0i + 1;
    bool vy0 = (y0 >= 0) & (y0 < Hh), vy1 = (y1 >= 0) & (y1 < Hh);
    bool vx0 = (x0i >= 0) & (x0i < Ww), vx1 = (x1 >= 0) & (x1 < Ww);
    W[0] = (vy0 & vx0) ? (1.0f - fy) * (1.0f - fx) : 0.0f;
    W[1] = (vy0 & vx1) ? (1.0f - fy) * fx : 0.0f;
    W[2] = (vy1 & vx0) ? fy * (1.0f - fx) : 0.0f;
    W[3] = (vy1 & vx1) ? fy * fx : 0.0f;
    int cy0 = min(max(y0, 0), Hh - 1), cy1 = min(max(y1, 0), Hh - 1);
    int cx0 = min(max(x0i, 0), Ww - 1), cx1 = min(max(x1, 0), Ww - 1);
    const unsigned short* s00 = xq + (size_t)(cy0 * Ww + cx0) * 64;
    const unsigned short* s01 = xq + (size_t)(cy0 * Ww + cx1) * 64;
    const unsigned short* s10 = xq + (size_t)(cy1 * Ww + cx0) * 64;
    const unsigned short* s11 = xq + (size_t)(cy1 * Ww + cx1) * 64;
    G[0] = *(const uint4*)(s00); G[1] = *(const uint4*)(s00 + 32);
    G[2] = *(const uint4*)(s01); G[3] = *(const uint4*)(s01 + 32);
    G[4] = *(const uint4*)(s10); G[5] = *(const uint4*)(s10 + 32);
    G[6] = *(const uint4*)(s11); G[7] = *(const uint4*)(s11 + 32);
}

__device__ inline void blend_frag(const uint4 G[8], const float W[4],
                                  bf16x8& A0, bf16x8& A1)
{
    uint4 o0, o1;
    o0.x = blend4(G[0].x, G[2].x, G[4].x, G[6].x, W[0], W[1], W[2], W[3]);
    o0.y = blend4(G[0].y, G[2].y, G[4].y, G[6].y, W[0], W[1], W[2], W[3]);
    o0.z = blend4(G[0].z, G[2].z, G[4].z, G[6].z, W[0], W[1], W[2], W[3]);
    o0.w = blend4(G[0].w, G[2].w, G[4].w, G[6].w, W[0], W[1], W[2], W[3]);
    o1.x = blend4(G[1].x, G[3].x, G[5].x, G[7].x, W[0], W[1], W[2], W[3]);
    o1.y = blend4(G[1].y, G[3].y, G[5].y, G[7].y, W[0], W[1], W[2], W[3]);
    o1.z = blend4(G[1].z, G[3].z, G[5].z, G[7].z, W[0], W[1], W[2], W[3]);
    o1.w = blend4(G[1].w, G[3].w, G[5].w, G[7].w, W[0], W[1], W[2], W[3]);
    A0 = as_bf(o0);
    A1 = as_bf(o1);
}

#define MFMA(A, B, C) __builtin_amdgcn_mfma_f32_16x16x32_bf16(A, B, C, 0, 0, 0)

// ---- fused: offset-conv + deform-sample + projection + BN + ReLU --------------
// 256 thr = 4 waves, 64 px/block, 16 px/wave. NO LDS weights, NO barriers in
// K-loops (weights pre-swizzled to per-lane B-fragment order -> dense 1KB wave
// loads from L1/L2). One __syncthreads total (offset handoff). Explicit
// next-tap gather prefetch.
__global__ __launch_bounds__(256, 4) void dcn_kernel(
    const unsigned short* __restrict__ xhwc,
    const unsigned short* __restrict__ wtbL,    // [9][2][4][16][4] chunks
    const unsigned short* __restrict__ woffL,   // [9][2][2][16][4] chunks
    const float* __restrict__ b_off,
    const float* __restrict__ scaleb,
    float* __restrict__ out)
{
    __shared__ float offb[64 * 20];            // 5120 B, stride 20 -> 8B-aligned f32x2

    const int t = threadIdx.x;
    const int lane = t & 63, wv = t >> 6;
    const int m = lane & 15, quad = lane >> 4;
    const int lc = (m * 4 + quad) * 8;         // this lane's weight-chunk offset

    int blk = blockIdx.x;
    int nb  = (blk & 7) * 400 + (blk >> 3);    // XCD slab swizzle: 1 image/XCD
    int b   = nb / 400;
    int hw0 = (nb % 400) * 64;
    int p   = wv * 16 + m;                     // this lane's pixel
    int hw  = hw0 + p;
    int h   = hw / Ww, w = hw % Ww;

    const unsigned short* xq = xhwc + ((size_t)b * HW) * 64 + quad * 8;

    // ============ phase 1: offset conv — barrier-free, weights from L2 ========
    f32x4 oa0 = {0,0,0,0}, oa1 = {0,0,0,0};
#pragma unroll
    for (int k = 0; k < 9; ++k) {
        int hp = h + k / 3 - 1, wp = w + k % 3 - 1;
        bool ok = (hp >= 0) & (hp < Hh) & (wp >= 0) & (wp < Ww);
        const unsigned short* s =
            xq + (size_t)(min(max(hp, 0), Hh - 1) * Ww + min(max(wp, 0), Ww - 1)) * 64;
        uint4 r0 = *(const uint4*)(s), r1 = *(const uint4*)(s + 32);
        if (!ok) { r0 = make_uint4(0,0,0,0); r1 = make_uint4(0,0,0,0); }
        bf16x8 A0 = as_bf(r0), A1 = as_bf(r1);

        const unsigned short* wo = woffL + k * 2048 + lc;
        bf16x8 B0 = *(const bf16x8*)(wo);           // half0, nt2=0
        bf16x8 B1 = *(const bf16x8*)(wo + 1024);    // half1, nt2=0
        oa0 = MFMA(A0, B0, oa0);
        oa0 = MFMA(A1, B1, oa0);
        B0 = *(const bf16x8*)(wo + 512);            // half0, nt2=1
        B1 = *(const bf16x8*)(wo + 1536);           // half1, nt2=1
        oa1 = MFMA(A0, B0, oa1);
        oa1 = MFMA(A1, B1, oa1);
    }
    // D layout: col(=o)=m, row(=pixel)=quad*4+r -> offsets to LDS
    {
        float bo0 = b_off[m];
        float bo1 = (m < 2) ? b_off[16 + m] : 0.0f;
#pragma unroll
        for (int r = 0; r < 4; ++r) {
            int pp = wv * 16 + quad * 4 + r;
            offb[pp * 20 + m] = oa0[r] + bo0;
            if (m < 2) offb[pp * 20 + 16 + m] = oa1[r] + bo1;
        }
    }
    __syncthreads();                               // the only barrier

    // ============ phase 2: deform sample + projection, prefetched =============
    f32x4 c0 = {0,0,0,0}, c1 = {0,0,0,0}, c2 = {0,0,0,0}, c3 = {0,0,0,0};
    uint4 G[8]; float W[4];
    {
        f32x2 of = *(const f32x2*)&offb[p * 20];
        gather_tap(xq, (float)(h - 1) + of.x, (float)(w - 1) + of.y, G, W);
    }
#pragma unroll
    for (int k = 0; k < 9; ++k) {
        uint4 Gn[8]; float Wn[4];
        if (k < 8) {    // prefetch next tap's corners while this tap computes
            f32x2 of = *(const f32x2*)&offb[p * 20 + 2 * (k + 1)];
            gather_tap(xq, (float)(h + (k + 1) / 3 - 1) + of.x,
                           (float)(w + (k + 1) % 3 - 1) + of.y, Gn, Wn);
        }
        bf16x8 A0, A1;
        blend_frag(G, W, A0, A1);

        const unsigned short* wk = wtbL + k * 4096 + lc;
        bf16x8 B0, B1;
        B0 = *(const bf16x8*)(wk);         B1 = *(const bf16x8*)(wk + 2048);
        c0 = MFMA(A0, B0, c0); c0 = MFMA(A1, B1, c0);
        B0 = *(const bf16x8*)(wk + 512);   B1 = *(const bf16x8*)(wk + 2560);
        c1 = MFMA(A0, B0, c1); c1 = MFMA(A1, B1, c1);
        B0 = *(const bf16x8*)(wk + 1024);  B1 = *(const bf16x8*)(wk + 3072);
        c2 = MFMA(A0, B0, c2); c2 = MFMA(A1, B1, c2);
        B0 = *(const bf16x8*)(wk + 1536);  B1 = *(const bf16x8*)(wk + 3584);
        c3 = MFMA(A0, B0, c3); c3 = MFMA(A1, B1, c3);

        if (k < 8) {
#pragma unroll
            for (int q = 0; q < 8; ++q) G[q] = Gn[q];
#pragma unroll
            for (int q = 0; q < 4; ++q) W[q] = Wn[q];
        }
    }

    // ---- epilogue: fused BN + ReLU, direct float4 stores ----
#pragma unroll
    for (int nt = 0; nt < 4; ++nt) {
        f32x4 a = (nt == 0) ? c0 : (nt == 1) ? c1 : (nt == 2) ? c2 : c3;
        int o = nt * 16 + m;
        float sc = scaleb[o];
        float bs = scaleb[Oo + o];
        float4 r;
        r.x = fmaxf(a[0] * sc + bs, 0.0f);
        r.y = fmaxf(a[1] * sc + bs, 0.0f);
        r.z = fmaxf(a[2] * sc + bs, 0.0f);
        r.w = fmaxf(a[3] * sc + bs, 0.0f);
        float* op = out + ((size_t)b * Oo + o) * HW + hw0 + wv * 16 + quad * 4;
        *(float4*)op = r;
    }
}

extern "C" void kernel_launch(void* const* d_in, const int* in_sizes, int n_in,
                              void* d_out, int out_size, void* d_ws, size_t ws_size,
                              hipStream_t stream) {
    const float* x        = (const float*)d_in[0];
    const float* w_off    = (const float*)d_in[1];
    const float* b_off    = (const float*)d_in[2];
    const float* w_dcn    = (const float*)d_in[3];
    const float* b_dcn    = (const float*)d_in[4];
    const float* gamma    = (const float*)d_in[5];
    const float* beta     = (const float*)d_in[6];
    const float* run_mean = (const float*)d_in[7];
    const float* run_var  = (const float*)d_in[8];
    float* out = (float*)d_out;

    // workspace: xhwc (26.2 MB) | wtbL | woffL | scaleb
    unsigned short* xhwc  = (unsigned short*)d_ws;
    unsigned short* wtbL  = xhwc + (size_t)NPIX * 64;     // 9*4096 bf16
    unsigned short* woffL = wtbL + 9 * 4096;              // 9*2048 bf16
    float* scaleb         = (float*)(woffL + 9 * 2048);   // 128 floats

    init_kernel<<<3200 + 144, 256, 0, stream>>>(
        x, xhwc, w_dcn, b_dcn, w_off, gamma, beta, run_mean, run_var,
        wtbL, woffL, scaleb);

    dcn_kernel<<<NPIX / 64, 256, 0, stream>>>(xhwc, wtbL, woffL, b_off, scaleb, out);
}